// Round 1
// baseline (657.433 us; speedup 1.0000x reference)
//
#include <hip/hip_runtime.h>
#include <math.h>

// Problem constants (B=4, C=192, H=W=128, KS=3, dilations {1,2,3}, 6 heads)
#define Hdim 128
#define Wdim 128
#define HW   16384
#define Cdim 192
#define Bdim 4
#define QKVC 576   // 3*C

// ---------------------------------------------------------------------------
// Kernel A: depthwise 3x3 conv (zero pad) + bias + residual
// xb[b,c,h,w] = x + conv(x, pos_w) + pos_b[c]
// ---------------------------------------------------------------------------
__global__ void posconv_kernel(const float* __restrict__ x,
                               const float* __restrict__ pos_w,
                               const float* __restrict__ pos_b,
                               float* __restrict__ xb) {
    int idx = blockIdx.x * 256 + threadIdx.x;   // over B*C*HW
    int p  = idx & (HW - 1);
    int bc = idx >> 14;           // b*C + c
    int c  = bc % Cdim;
    int h  = p >> 7, w = p & 127;
    const float* xc = x + (size_t)bc * HW;
    const float* wt = pos_w + c * 9;
    float acc = 0.f;
#pragma unroll
    for (int kh = 0; kh < 3; ++kh) {
        int hh = h + kh - 1;
        if (hh < 0 || hh >= Hdim) continue;   // zero padding
#pragma unroll
        for (int kw = 0; kw < 3; ++kw) {
            int ww = w + kw - 1;
            if (ww < 0 || ww >= Wdim) continue;
            acc += xc[hh * Wdim + ww] * wt[kh * 3 + kw];
        }
    }
    xb[idx] = xc[p] + acc + pos_b[c];
}

// ---------------------------------------------------------------------------
// Tiled f32 GEMM: C[b][m,p] = sum_c W[m,c] * X[b][c,p],  K = Cdim = 192
// BM=BN=64, BK=32, 256 threads, 4x4 micro-tile per thread.
// ---------------------------------------------------------------------------
#define BM 64
#define BN 64
#define BK 32
__global__ void gemm_kernel(const float* __restrict__ Wmat,  // [M, 192]
                            const float* __restrict__ X,     // [B][192, HW]
                            float* __restrict__ C,           // [B][M, HW]
                            int M) {
    __shared__ float Ws[BK][BM + 1];   // +1 pad: stride-65 kills bank conflicts
    __shared__ float Xs[BK][BN];
    int b = blockIdx.z;
    const float* Xb = X + (size_t)b * Cdim * HW;
    float* Cb = C + (size_t)b * M * HW;
    int row0 = blockIdx.y * BM;
    int col0 = blockIdx.x * BN;
    int tid = threadIdx.x;
    int tx = tid & 15, ty = tid >> 4;
    float acc[4][4] = {};

    for (int k0 = 0; k0 < Cdim; k0 += BK) {
        // stage W tile: Ws[kk][m] = W[row0+m, k0+kk]  (kk fastest -> coalesced)
#pragma unroll
        for (int t = 0; t < (BM * BK) / 256; ++t) {
            int idx = t * 256 + tid;
            int kk = idx & (BK - 1);
            int m  = idx >> 5;
            Ws[kk][m] = Wmat[(size_t)(row0 + m) * Cdim + k0 + kk];
        }
        // stage X tile: Xs[kk][n] = X[k0+kk, col0+n]  (n fastest -> coalesced)
#pragma unroll
        for (int t = 0; t < (BK * BN) / 256; ++t) {
            int idx = t * 256 + tid;
            int n  = idx & (BN - 1);
            int kk = idx >> 6;
            Xs[kk][n] = Xb[(size_t)(k0 + kk) * HW + col0 + n];
        }
        __syncthreads();
#pragma unroll
        for (int kk = 0; kk < BK; ++kk) {
            float wf[4], xf[4];
#pragma unroll
            for (int i = 0; i < 4; ++i) wf[i] = Ws[kk][ty * 4 + i];
#pragma unroll
            for (int j = 0; j < 4; ++j) xf[j] = Xs[kk][tx * 4 + j];
#pragma unroll
            for (int i = 0; i < 4; ++i)
#pragma unroll
                for (int j = 0; j < 4; ++j)
                    acc[i][j] += wf[i] * xf[j];
        }
        __syncthreads();
    }
#pragma unroll
    for (int i = 0; i < 4; ++i) {
        int r = row0 + ty * 4 + i;
#pragma unroll
        for (int j = 0; j < 4; ++j)
            Cb[(size_t)r * HW + col0 + tx * 4 + j] = acc[i][j];
    }
}

// ---------------------------------------------------------------------------
// Kernel C: multi-dilation window attention.
// One thread per (b, dilation i, head n, pixel p).
// QKV layout: channel o = three*192 + i*64 + n*32 + d, [B, 576, HW].
// AO layout:  channel    = i*64 + n*32 + d,            [B, 192, HW].
// ---------------------------------------------------------------------------
__global__ void attn_kernel(const float* __restrict__ QKV,
                            float* __restrict__ AO) {
    int tid = threadIdx.x;
    int p = blockIdx.x * 256 + tid;
    int comb = blockIdx.y;          // i*2 + n
    int b = blockIdx.z;
    int i = comb >> 1, n = comb & 1;
    int dil = i + 1;
    int h = p >> 7, w = p & 127;

    size_t base = ((size_t)b * QKVC + (size_t)i * 64 + n * 32) * HW;
    const float* Q  = QKV + base;
    const float* Kp = QKV + base + (size_t)Cdim * HW;       // +192 channels
    const float* Vp = QKV + base + (size_t)2 * Cdim * HW;   // +384 channels

    float q[32];
#pragma unroll
    for (int d = 0; d < 32; ++d) q[d] = Q[(size_t)d * HW + p];

    // reflect-padded dilated 3x3 neighborhood
    int pj[9];
#pragma unroll
    for (int kh = 0; kh < 3; ++kh) {
        int hh = h + (kh - 1) * dil;
        hh = hh < 0 ? -hh : (hh >= Hdim ? 2 * Hdim - 2 - hh : hh);
#pragma unroll
        for (int kw = 0; kw < 3; ++kw) {
            int ww = w + (kw - 1) * dil;
            ww = ww < 0 ? -ww : (ww >= Wdim ? 2 * Wdim - 2 - ww : ww);
            pj[kh * 3 + kw] = hh * Wdim + ww;
        }
    }

    float sc[9];
#pragma unroll
    for (int j = 0; j < 9; ++j) {
        float s = 0.f;
#pragma unroll
        for (int d = 0; d < 32; ++d) s += q[d] * Kp[(size_t)d * HW + pj[j]];
        sc[j] = s * 0.17677669529663687f;   // 32^-0.5
    }
    float m = sc[0];
#pragma unroll
    for (int j = 1; j < 9; ++j) m = fmaxf(m, sc[j]);
    float sum = 0.f;
#pragma unroll
    for (int j = 0; j < 9; ++j) { sc[j] = __expf(sc[j] - m); sum += sc[j]; }
    float inv = 1.f / sum;

    float acc[32] = {};
#pragma unroll
    for (int j = 0; j < 9; ++j) {
        float a = sc[j] * inv;
#pragma unroll
        for (int d = 0; d < 32; ++d) acc[d] += a * Vp[(size_t)d * HW + pj[j]];
    }
    size_t obase = ((size_t)b * Cdim + i * 64 + n * 32) * HW + p;
#pragma unroll
    for (int d = 0; d < 32; ++d) AO[obase + (size_t)d * HW] = acc[d];
}

// ---------------------------------------------------------------------------
extern "C" void kernel_launch(void* const* d_in, const int* in_sizes, int n_in,
                              void* d_out, int out_size, void* d_ws, size_t ws_size,
                              hipStream_t stream) {
    const float* x      = (const float*)d_in[0];
    const float* pos_w  = (const float*)d_in[1];
    const float* pos_b  = (const float*)d_in[2];
    const float* qkv_w  = (const float*)d_in[3];
    const float* proj_w = (const float*)d_in[4];
    float* out = (float*)d_out;

    // ws layout: QKV f32 [4,576,16384] = 144 MiB, then X/AO shared 48 MiB
    char* ws = (char*)d_ws;
    float* QKV = (float*)ws;
    float* Xb  = (float*)(ws + (size_t)Bdim * QKVC * HW * sizeof(float));
    float* AO  = Xb;   // lifetimes disjoint: Xb dead after qkv GEMM

    // A: pos conv + residual
    posconv_kernel<<<(Bdim * Cdim * HW) / 256, 256, 0, stream>>>(x, pos_w, pos_b, Xb);

    // B: qkv 1x1 conv (GEMM M=576)
    dim3 gq(HW / BN, QKVC / BM, Bdim);
    gemm_kernel<<<gq, 256, 0, stream>>>(qkv_w, Xb, QKV, QKVC);

    // C: attention for all 3 dilations x 2 heads
    dim3 ga(HW / 256, 6, Bdim);
    attn_kernel<<<ga, 256, 0, stream>>>(QKV, AO);

    // D: output projection (GEMM M=192)
    dim3 gp(HW / BN, Cdim / BM, Bdim);
    gemm_kernel<<<gp, 256, 0, stream>>>(proj_w, AO, out, Cdim);
}

// Round 2
// 615.864 us; speedup vs baseline: 1.0675x; 1.0675x over previous
//
#include <hip/hip_runtime.h>
#include <hip/hip_bf16.h>
#include <math.h>

// Problem constants (B=4, C=192, H=W=128, KS=3, dilations {1,2,3}, 6 heads)
#define Hdim 128
#define Wdim 128
#define HW   16384
#define Cdim 192
#define Bdim 4
#define QKVC 576            // 3*C
#define NTOT (Bdim * HW)    // 65536 total pixels

typedef __attribute__((ext_vector_type(8))) short short8;   // 8 bf16 (4 VGPRs)
typedef __attribute__((ext_vector_type(4))) float f32x4;

__device__ __forceinline__ void async_ld16(void* lds, const void* g) {
    __builtin_amdgcn_global_load_lds(
        (const __attribute__((address_space(1))) void*)g,
        (__attribute__((address_space(3))) void*)lds, 16, 0, 0);
}

// ---------------------------------------------------------------------------
// Convert both weight matrices to bf16 (147456 elements total).
// ---------------------------------------------------------------------------
__global__ void convert_w(const float* __restrict__ qkv_w,
                          const float* __restrict__ proj_w,
                          __hip_bfloat16* __restrict__ Wq,
                          __hip_bfloat16* __restrict__ Wp) {
    int i = blockIdx.x * 256 + threadIdx.x;
    if (i < QKVC * Cdim) {
        Wq[i] = __float2bfloat16(qkv_w[i]);
    } else {
        int j = i - QKVC * Cdim;
        Wp[j] = __float2bfloat16(proj_w[j]);
    }
}

// ---------------------------------------------------------------------------
// posconv: depthwise 3x3 (zero pad) + bias + residual, f32 in NCHW ->
// bf16 out NHWC [NTOT][192] via LDS transpose (coalesced both sides).
// Block: 256 threads, 64 pixels x 192 channels.
// ---------------------------------------------------------------------------
__global__ __launch_bounds__(256, 2)
void posconv_nhwc(const float* __restrict__ x,
                  const float* __restrict__ pos_w,
                  const float* __restrict__ pos_b,
                  __hip_bfloat16* __restrict__ Xb) {
    __shared__ float tile[64][193];   // +1 pad: phase-1 writes stride 193
    int p0 = blockIdx.x * 64;         // global pixel base
    int b = p0 >> 14;
    int pimg = p0 & (HW - 1);
    int h = pimg >> 7, w0 = pimg & 127;   // 64 pixels share one row h
    const float* xb_ = x + (size_t)b * Cdim * HW;
    int t = threadIdx.x;

    // phase 1: conv, NCHW coalesced reads -> LDS [pixel][channel]
    for (int it = 0; it < 48; ++it) {
        int idx = it * 256 + t;
        int c = idx >> 6, pl = idx & 63;
        int wc = w0 + pl;
        const float* xc = xb_ + (size_t)c * HW;
        const float* wt = pos_w + c * 9;
        float acc = xc[h * Wdim + wc] + pos_b[c];
#pragma unroll
        for (int kh = 0; kh < 3; ++kh) {
            int hh = h + kh - 1;
            if (hh < 0 || hh >= Hdim) continue;   // zero padding
#pragma unroll
            for (int kw = 0; kw < 3; ++kw) {
                int ww = wc + kw - 1;
                if (ww < 0 || ww >= Wdim) continue;
                acc += xc[hh * Wdim + ww] * wt[kh * 3 + kw];
            }
        }
        tile[pl][c] = acc;
    }
    __syncthreads();
    // phase 2: NHWC coalesced bf16 writes
    for (int it = 0; it < 48; ++it) {
        int idx = it * 256 + t;
        int pl = idx / Cdim, c = idx % Cdim;
        Xb[(size_t)(p0 + pl) * Cdim + c] = __float2bfloat16(tile[pl][c]);
    }
}

// ---------------------------------------------------------------------------
// MFMA bf16 GEMM: D[m,n] = sum_k W[m,k] * Xt[n,k]    (K = 192)
// W: [M][192] bf16 row-major; Xt: [NTOT][192] bf16 row-major (NHWC).
// Block 64x256 (4 waves of 64x64, 4x4 frags of 16x16x32). BK=32, 6 K-iters.
// MODE 0: store bf16 [M][NTOT] (QKV, channel-major).
// MODE 1: store f32 NCHW out[b][m][p], col n = b*HW + p.
// ---------------------------------------------------------------------------
template <int MODE>
__global__ __launch_bounds__(256, 2)
void gemm_mfma(const __hip_bfloat16* __restrict__ Wb,
               const __hip_bfloat16* __restrict__ Xt,
               void* __restrict__ Cout) {
    __shared__ __hip_bfloat16 As[64 * 32];    // [m][k], rows of 32 bf16 (64 B)
    __shared__ __hip_bfloat16 Bs[256 * 32];   // [n][k]
    const int t = threadIdx.x;
    const int w = t >> 6, l = t & 63;
    const int lq = l >> 4, lr = l & 15;
    const int m0 = blockIdx.y * 64;
    const int n0 = blockIdx.x * 256;

    f32x4 acc[4][4] = {};

    for (int kt = 0; kt < 6; ++kt) {
        const int k0 = kt * 32;
        // stage A tile: 64x32 bf16 = 4 KB = 256 threads x 16 B
        {
            int m = t >> 2, kc = t & 3;
            async_ld16(As + t * 8, Wb + (size_t)(m0 + m) * Cdim + k0 + kc * 8);
        }
        // stage B tile: 256x32 bf16 = 16 KB = 4 x (256 threads x 16 B)
#pragma unroll
        for (int it = 0; it < 4; ++it) {
            int idx = it * 256 + t;
            int n = idx >> 2, kc = idx & 3;
            async_ld16(Bs + idx * 8, Xt + (size_t)(n0 + n) * Cdim + k0 + kc * 8);
        }
        __syncthreads();   // compiler drains vmcnt before s_barrier

        short8 af[4], bf[4];
#pragma unroll
        for (int i = 0; i < 4; ++i)
            af[i] = *(const short8*)(void*)(As + (i * 16 + lr) * 32 + lq * 8);
#pragma unroll
        for (int j = 0; j < 4; ++j)
            bf[j] = *(const short8*)(void*)(Bs + (w * 64 + j * 16 + lr) * 32 + lq * 8);
#pragma unroll
        for (int i = 0; i < 4; ++i)
#pragma unroll
            for (int j = 0; j < 4; ++j)
                acc[i][j] = __builtin_amdgcn_mfma_f32_16x16x32_bf16(
                    af[i], bf[j], acc[i][j], 0, 0, 0);
        __syncthreads();
    }

    // epilogue: D col = lane&15, row = (lane>>4)*4 + r  (m89/m91-verified)
#pragma unroll
    for (int i = 0; i < 4; ++i) {
#pragma unroll
        for (int j = 0; j < 4; ++j) {
            int n = n0 + w * 64 + j * 16 + lr;
#pragma unroll
            for (int r = 0; r < 4; ++r) {
                int m = m0 + i * 16 + lq * 4 + r;
                if (MODE == 0) {
                    ((__hip_bfloat16*)Cout)[(size_t)m * NTOT + n] =
                        __float2bfloat16(acc[i][j][r]);
                } else {
                    int b = n >> 14, p = n & (HW - 1);
                    ((float*)Cout)[((size_t)(b * Cdim + m)) * HW + p] = acc[i][j][r];
                }
            }
        }
    }
}

// ---------------------------------------------------------------------------
// Attention: one thread per (b, dilation i, head nh, pixel p).
// QKV bf16 channel-major [576][NTOT]; col = b*HW + p.
// Output AO bf16 NHWC [NTOT][192], channel = i*64 + nh*32 + d.
// ---------------------------------------------------------------------------
__global__ __launch_bounds__(256, 2)
void attn_kernel(const __hip_bfloat16* __restrict__ QKV,
                 __hip_bfloat16* __restrict__ AO) {
    int t = threadIdx.x;
    int p = blockIdx.x * 256 + t;
    int comb = blockIdx.y;          // i*2 + nh
    int b = blockIdx.z;
    int i = comb >> 1, nh = comb & 1;
    int dil = i + 1;
    int h = p >> 7, w = p & 127;
    int col = (b << 14) + p;

    const __hip_bfloat16* Q = QKV + (size_t)(i * 64 + nh * 32) * NTOT;
    const __hip_bfloat16* K = Q + (size_t)Cdim * NTOT;
    const __hip_bfloat16* V = K + (size_t)Cdim * NTOT;

    float q[32];
#pragma unroll
    for (int d = 0; d < 32; ++d) q[d] = __bfloat162float(Q[(size_t)d * NTOT + col]);

    // reflect-padded dilated 3x3 neighborhood (within the b-th image)
    int cj[9];
#pragma unroll
    for (int kh = 0; kh < 3; ++kh) {
        int hh = h + (kh - 1) * dil;
        hh = hh < 0 ? -hh : (hh >= Hdim ? 2 * Hdim - 2 - hh : hh);
#pragma unroll
        for (int kw = 0; kw < 3; ++kw) {
            int ww = w + (kw - 1) * dil;
            ww = ww < 0 ? -ww : (ww >= Wdim ? 2 * Wdim - 2 - ww : ww);
            cj[kh * 3 + kw] = (b << 14) + hh * Wdim + ww;
        }
    }

    float sc[9];
#pragma unroll
    for (int j = 0; j < 9; ++j) {
        float s = 0.f;
#pragma unroll
        for (int d = 0; d < 32; ++d)
            s += q[d] * __bfloat162float(K[(size_t)d * NTOT + cj[j]]);
        sc[j] = s * 0.17677669529663687f;   // 32^-0.5
    }
    float m = sc[0];
#pragma unroll
    for (int j = 1; j < 9; ++j) m = fmaxf(m, sc[j]);
    float sum = 0.f;
#pragma unroll
    for (int j = 0; j < 9; ++j) { sc[j] = __expf(sc[j] - m); sum += sc[j]; }
    float inv = 1.f / sum;

    float acc[32] = {};
#pragma unroll
    for (int j = 0; j < 9; ++j) {
        float a = sc[j];
#pragma unroll
        for (int d = 0; d < 32; ++d)
            acc[d] += a * __bfloat162float(V[(size_t)d * NTOT + cj[j]]);
    }

    // NHWC store: 32 contiguous bf16 = 64 B per thread, 16B-aligned
    union { unsigned short h[32]; short8 v[4]; } o;
#pragma unroll
    for (int d = 0; d < 32; ++d) {
        __hip_bfloat16 bv = __float2bfloat16(acc[d] * inv);
        o.h[d] = *(unsigned short*)&bv;
    }
    short8* dst = (short8*)(void*)(AO + (size_t)col * Cdim + i * 64 + nh * 32);
#pragma unroll
    for (int u = 0; u < 4; ++u) dst[u] = o.v[u];
}

// ---------------------------------------------------------------------------
extern "C" void kernel_launch(void* const* d_in, const int* in_sizes, int n_in,
                              void* d_out, int out_size, void* d_ws, size_t ws_size,
                              hipStream_t stream) {
    const float* x      = (const float*)d_in[0];
    const float* pos_w  = (const float*)d_in[1];
    const float* pos_b  = (const float*)d_in[2];
    const float* qkv_w  = (const float*)d_in[3];
    const float* proj_w = (const float*)d_in[4];
    float* out = (float*)d_out;

    // ws layout (bytes): Xb 24 MiB | QKV 72 MiB | AO 24 MiB | Wq | Wp
    char* ws = (char*)d_ws;
    __hip_bfloat16* Xb  = (__hip_bfloat16*)ws;                            // [NTOT][192]
    __hip_bfloat16* QKV = (__hip_bfloat16*)(ws + (size_t)25165824);       // [576][NTOT]
    __hip_bfloat16* AO  = (__hip_bfloat16*)(ws + (size_t)100663296);      // [NTOT][192]
    __hip_bfloat16* Wq  = (__hip_bfloat16*)(ws + (size_t)125829120);      // [576][192]
    __hip_bfloat16* Wp  = (__hip_bfloat16*)(ws + (size_t)126050304);      // [192][192]

    convert_w<<<(QKVC * Cdim + Cdim * Cdim) / 256, 256, 0, stream>>>(
        qkv_w, proj_w, Wq, Wp);

    posconv_nhwc<<<NTOT / 64, 256, 0, stream>>>(x, pos_w, pos_b, Xb);

    dim3 gq(NTOT / 256, QKVC / 64);
    gemm_mfma<0><<<gq, 256, 0, stream>>>(Wq, Xb, QKV);

    dim3 ga(HW / 256, 6, Bdim);
    attn_kernel<<<ga, 256, 0, stream>>>(QKV, AO);

    dim3 gp(NTOT / 256, Cdim / 64);
    gemm_mfma<1><<<gp, 256, 0, stream>>>(Wp, AO, out);
}

// Round 3
// 447.417 us; speedup vs baseline: 1.4694x; 1.3765x over previous
//
#include <hip/hip_runtime.h>
#include <hip/hip_bf16.h>
#include <math.h>

// Problem constants (B=4, C=192, H=W=128, KS=3, dilations {1,2,3}, 6 heads)
#define Hdim 128
#define Wdim 128
#define HW   16384
#define Cdim 192
#define Bdim 4
#define QKVC 576            // 3*C
#define NTOT (Bdim * HW)    // 65536 total pixels

typedef __attribute__((ext_vector_type(8))) short short8;   // 8 bf16 (4 VGPRs)
typedef __attribute__((ext_vector_type(4))) short short4v;  // 4 bf16 (8 B)
typedef __attribute__((ext_vector_type(4))) float f32x4;

__device__ __forceinline__ void async_ld16(void* lds, const void* g) {
    __builtin_amdgcn_global_load_lds(
        (const __attribute__((address_space(1))) void*)g,
        (__attribute__((address_space(3))) void*)lds, 16, 0, 0);
}
__device__ __forceinline__ float lo16(unsigned u) { return __uint_as_float(u << 16); }
__device__ __forceinline__ float hi16(unsigned u) { return __uint_as_float(u & 0xffff0000u); }

// ---------------------------------------------------------------------------
// Convert both weight matrices to bf16 (147456 elements total).
// ---------------------------------------------------------------------------
__global__ void convert_w(const float* __restrict__ qkv_w,
                          const float* __restrict__ proj_w,
                          __hip_bfloat16* __restrict__ Wq,
                          __hip_bfloat16* __restrict__ Wp) {
    int i = blockIdx.x * 256 + threadIdx.x;
    if (i < QKVC * Cdim) {
        Wq[i] = __float2bfloat16(qkv_w[i]);
    } else {
        int j = i - QKVC * Cdim;
        Wp[j] = __float2bfloat16(proj_w[j]);
    }
}

// ---------------------------------------------------------------------------
// posconv: depthwise 3x3 (zero pad) + bias + residual, f32 in NCHW ->
// bf16 out NHWC [NTOT][192] via LDS transpose (coalesced both sides).
// ---------------------------------------------------------------------------
__global__ __launch_bounds__(256, 2)
void posconv_nhwc(const float* __restrict__ x,
                  const float* __restrict__ pos_w,
                  const float* __restrict__ pos_b,
                  __hip_bfloat16* __restrict__ Xb) {
    __shared__ float tile[64][193];
    int p0 = blockIdx.x * 64;
    int b = p0 >> 14;
    int pimg = p0 & (HW - 1);
    int h = pimg >> 7, w0 = pimg & 127;
    const float* xb_ = x + (size_t)b * Cdim * HW;
    int t = threadIdx.x;

    for (int it = 0; it < 48; ++it) {
        int idx = it * 256 + t;
        int c = idx >> 6, pl = idx & 63;
        int wc = w0 + pl;
        const float* xc = xb_ + (size_t)c * HW;
        const float* wt = pos_w + c * 9;
        float acc = xc[h * Wdim + wc] + pos_b[c];
#pragma unroll
        for (int kh = 0; kh < 3; ++kh) {
            int hh = h + kh - 1;
            if (hh < 0 || hh >= Hdim) continue;
#pragma unroll
            for (int kw = 0; kw < 3; ++kw) {
                int ww = wc + kw - 1;
                if (ww < 0 || ww >= Wdim) continue;
                acc += xc[hh * Wdim + ww] * wt[kh * 3 + kw];
            }
        }
        tile[pl][c] = acc;
    }
    __syncthreads();
    for (int it = 0; it < 48; ++it) {
        int idx = it * 256 + t;
        int pl = idx / Cdim, c = idx % Cdim;
        Xb[(size_t)(p0 + pl) * Cdim + c] = __float2bfloat16(tile[pl][c]);
    }
}

// ---------------------------------------------------------------------------
// MFMA bf16 GEMM: D[m,n] = sum_k W[m,k] * Xt[n,k]    (K = 192)
// Block 64x256 (4 waves of 64x64, 4x4 frags of 16x16x32). BK=32, 6 K-iters.
// MODE 0: store bf16 plane layout [(three*3+i)*2+nh][NTOT][32]; m =
//         three*192 + i*64 + nh*32 + d. 8B packed stores (4 channels).
// MODE 1: store f32 NCHW out[b][m][p], col n = b*HW + p.
// ---------------------------------------------------------------------------
template <int MODE>
__global__ __launch_bounds__(256, 2)
void gemm_mfma(const __hip_bfloat16* __restrict__ Wb,
               const __hip_bfloat16* __restrict__ Xt,
               void* __restrict__ Cout) {
    __shared__ __hip_bfloat16 As[64 * 32];
    __shared__ __hip_bfloat16 Bs[256 * 32];
    const int t = threadIdx.x;
    const int w = t >> 6, l = t & 63;
    const int lq = l >> 4, lr = l & 15;
    const int m0 = blockIdx.y * 64;
    const int n0 = blockIdx.x * 256;

    f32x4 acc[4][4] = {};

    for (int kt = 0; kt < 6; ++kt) {
        const int k0 = kt * 32;
        {
            int m = t >> 2, kc = t & 3;
            async_ld16(As + t * 8, Wb + (size_t)(m0 + m) * Cdim + k0 + kc * 8);
        }
#pragma unroll
        for (int it = 0; it < 4; ++it) {
            int idx = it * 256 + t;
            int n = idx >> 2, kc = idx & 3;
            async_ld16(Bs + idx * 8, Xt + (size_t)(n0 + n) * Cdim + k0 + kc * 8);
        }
        __syncthreads();

        short8 af[4], bf[4];
#pragma unroll
        for (int i = 0; i < 4; ++i)
            af[i] = *(const short8*)(void*)(As + (i * 16 + lr) * 32 + lq * 8);
#pragma unroll
        for (int j = 0; j < 4; ++j)
            bf[j] = *(const short8*)(void*)(Bs + (w * 64 + j * 16 + lr) * 32 + lq * 8);
#pragma unroll
        for (int i = 0; i < 4; ++i)
#pragma unroll
            for (int j = 0; j < 4; ++j)
                acc[i][j] = __builtin_amdgcn_mfma_f32_16x16x32_bf16(
                    af[i], bf[j], acc[i][j], 0, 0, 0);
        __syncthreads();
    }

    // epilogue: D col = lane&15, row = (lane>>4)*4 + r  (m89/m91-verified)
#pragma unroll
    for (int i = 0; i < 4; ++i) {
        int mb = m0 + i * 16 + lq * 4;            // 4 consecutive m (r=0..3)
#pragma unroll
        for (int j = 0; j < 4; ++j) {
            int n = n0 + w * 64 + j * 16 + lr;
            if (MODE == 0) {
                int three = mb / 192, rem = mb % 192;
                int pi = rem >> 6, pn = (rem >> 5) & 1, d4 = rem & 31;
                size_t plane = (size_t)((three * 3 + pi) * 2 + pn);
                __hip_bfloat16* dst = (__hip_bfloat16*)Cout +
                    plane * ((size_t)NTOT * 32) + (size_t)n * 32 + d4;
                short4v pk;
#pragma unroll
                for (int r = 0; r < 4; ++r) {
                    __hip_bfloat16 bv = __float2bfloat16(acc[i][j][r]);
                    pk[r] = *(short*)&bv;
                }
                *(short4v*)(void*)dst = pk;
            } else {
                int b = n >> 14, p = n & (HW - 1);
#pragma unroll
                for (int r = 0; r < 4; ++r)
                    ((float*)Cout)[((size_t)(b * Cdim + mb + r)) * HW + p] =
                        acc[i][j][r];
            }
        }
    }
}

// ---------------------------------------------------------------------------
// Attention: one thread per (b, dilation i, head nh, pixel p).
// QKV bf16 planes [(three*3+i)*2+nh][NTOT][32]; per-thread Q/K/V rows are
// contiguous 64 B -> 4x dwordx4 loads. Output AO bf16 NHWC [NTOT][192].
// ---------------------------------------------------------------------------
__global__ __launch_bounds__(256, 2)
void attn_kernel(const __hip_bfloat16* __restrict__ QKV,
                 __hip_bfloat16* __restrict__ AO) {
    int t = threadIdx.x;
    int p = blockIdx.x * 256 + t;
    int comb = blockIdx.y;          // i*2 + nh
    int b = blockIdx.z;
    int i = comb >> 1, nh = comb & 1;
    int dil = i + 1;
    int h = p >> 7, w = p & 127;
    int col = (b << 14) + p;

    const size_t PS = (size_t)NTOT * 32;
    const __hip_bfloat16* Qp = QKV + (size_t)comb * PS;
    const __hip_bfloat16* Kp = Qp + 6 * PS;
    const __hip_bfloat16* Vp = Qp + 12 * PS;

    float q[32];
    {
        const uint4* qv = (const uint4*)(Qp + (size_t)col * 32);
#pragma unroll
        for (int u = 0; u < 4; ++u) {
            uint4 x = qv[u];
            q[u * 8 + 0] = lo16(x.x); q[u * 8 + 1] = hi16(x.x);
            q[u * 8 + 2] = lo16(x.y); q[u * 8 + 3] = hi16(x.y);
            q[u * 8 + 4] = lo16(x.z); q[u * 8 + 5] = hi16(x.z);
            q[u * 8 + 6] = lo16(x.w); q[u * 8 + 7] = hi16(x.w);
        }
    }

    // reflect-padded dilated 3x3 neighborhood (within the b-th image)
    int cj[9];
#pragma unroll
    for (int kh = 0; kh < 3; ++kh) {
        int hh = h + (kh - 1) * dil;
        hh = hh < 0 ? -hh : (hh >= Hdim ? 2 * Hdim - 2 - hh : hh);
#pragma unroll
        for (int kw = 0; kw < 3; ++kw) {
            int ww = w + (kw - 1) * dil;
            ww = ww < 0 ? -ww : (ww >= Wdim ? 2 * Wdim - 2 - ww : ww);
            cj[kh * 3 + kw] = (b << 14) + hh * Wdim + ww;
        }
    }

    float sc[9];
#pragma unroll
    for (int j = 0; j < 9; ++j) {
        const uint4* kv = (const uint4*)(Kp + (size_t)cj[j] * 32);
        float s = 0.f;
#pragma unroll
        for (int u = 0; u < 4; ++u) {
            uint4 x = kv[u];
            s += q[u * 8 + 0] * lo16(x.x) + q[u * 8 + 1] * hi16(x.x);
            s += q[u * 8 + 2] * lo16(x.y) + q[u * 8 + 3] * hi16(x.y);
            s += q[u * 8 + 4] * lo16(x.z) + q[u * 8 + 5] * hi16(x.z);
            s += q[u * 8 + 6] * lo16(x.w) + q[u * 8 + 7] * hi16(x.w);
        }
        sc[j] = s * 0.17677669529663687f;   // 32^-0.5
    }
    float m = sc[0];
#pragma unroll
    for (int j = 1; j < 9; ++j) m = fmaxf(m, sc[j]);
    float sum = 0.f;
#pragma unroll
    for (int j = 0; j < 9; ++j) { sc[j] = __expf(sc[j] - m); sum += sc[j]; }
    float inv = 1.f / sum;

    float acc[32] = {};
#pragma unroll
    for (int j = 0; j < 9; ++j) {
        const uint4* vv = (const uint4*)(Vp + (size_t)cj[j] * 32);
        float a = sc[j];
#pragma unroll
        for (int u = 0; u < 4; ++u) {
            uint4 x = vv[u];
            acc[u * 8 + 0] += a * lo16(x.x); acc[u * 8 + 1] += a * hi16(x.x);
            acc[u * 8 + 2] += a * lo16(x.y); acc[u * 8 + 3] += a * hi16(x.y);
            acc[u * 8 + 4] += a * lo16(x.z); acc[u * 8 + 5] += a * hi16(x.z);
            acc[u * 8 + 6] += a * lo16(x.w); acc[u * 8 + 7] += a * hi16(x.w);
        }
    }

    // NHWC store: 32 contiguous bf16 = 64 B, 16B-aligned
    union { unsigned short h[32]; short8 v[4]; } o;
#pragma unroll
    for (int d = 0; d < 32; ++d) {
        __hip_bfloat16 bv = __float2bfloat16(acc[d] * inv);
        o.h[d] = *(unsigned short*)&bv;
    }
    short8* dst = (short8*)(void*)(AO + (size_t)col * Cdim + i * 64 + nh * 32);
#pragma unroll
    for (int u = 0; u < 4; ++u) dst[u] = o.v[u];
}

// ---------------------------------------------------------------------------
extern "C" void kernel_launch(void* const* d_in, const int* in_sizes, int n_in,
                              void* d_out, int out_size, void* d_ws, size_t ws_size,
                              hipStream_t stream) {
    const float* x      = (const float*)d_in[0];
    const float* pos_w  = (const float*)d_in[1];
    const float* pos_b  = (const float*)d_in[2];
    const float* qkv_w  = (const float*)d_in[3];
    const float* proj_w = (const float*)d_in[4];
    float* out = (float*)d_out;

    // ws layout (bytes): Xb 24 MiB | QKV planes 72 MiB | AO 24 MiB | Wq | Wp
    char* ws = (char*)d_ws;
    __hip_bfloat16* Xb  = (__hip_bfloat16*)ws;                            // [NTOT][192]
    __hip_bfloat16* QKV = (__hip_bfloat16*)(ws + (size_t)25165824);       // [18][NTOT][32]
    __hip_bfloat16* AO  = (__hip_bfloat16*)(ws + (size_t)100663296);      // [NTOT][192]
    __hip_bfloat16* Wq  = (__hip_bfloat16*)(ws + (size_t)125829120);      // [576][192]
    __hip_bfloat16* Wp  = (__hip_bfloat16*)(ws + (size_t)126050304);      // [192][192]

    convert_w<<<(QKVC * Cdim + Cdim * Cdim) / 256, 256, 0, stream>>>(
        qkv_w, proj_w, Wq, Wp);

    posconv_nhwc<<<NTOT / 64, 256, 0, stream>>>(x, pos_w, pos_b, Xb);

    dim3 gq(NTOT / 256, QKVC / 64);
    gemm_mfma<0><<<gq, 256, 0, stream>>>(Wq, Xb, QKV);

    dim3 ga(HW / 256, 6, Bdim);
    attn_kernel<<<ga, 256, 0, stream>>>(QKV, AO);

    dim3 gp(NTOT / 256, Cdim / 64);
    gemm_mfma<1><<<gp, 256, 0, stream>>>(Wp, AO, out);
}

// Round 4
// 260.872 us; speedup vs baseline: 2.5201x; 1.7151x over previous
//
#include <hip/hip_runtime.h>
#include <hip/hip_bf16.h>
#include <math.h>

// Problem constants (B=4, C=192, H=W=128, KS=3, dilations {1,2,3}, 6 heads)
#define Hdim 128
#define Wdim 128
#define HW   16384
#define Cdim 192
#define Bdim 4
#define QKVC 576            // 3*C
#define NTOT (Bdim * HW)    // 65536 total pixels

typedef __attribute__((ext_vector_type(8))) short short8;   // 8 bf16 (4 VGPRs)
typedef __attribute__((ext_vector_type(4))) short short4v;  // 4 bf16 (8 B)
typedef __attribute__((ext_vector_type(4))) float f32x4;

__device__ __forceinline__ void async_ld16(void* lds, const void* g) {
    __builtin_amdgcn_global_load_lds(
        (const __attribute__((address_space(1))) void*)g,
        (__attribute__((address_space(3))) void*)lds, 16, 0, 0);
}
__device__ __forceinline__ float lo16(unsigned u) { return __uint_as_float(u << 16); }
__device__ __forceinline__ float hi16(unsigned u) { return __uint_as_float(u & 0xffff0000u); }

// ---------------------------------------------------------------------------
// Convert both weight matrices to bf16 (147456 elements total).
// ---------------------------------------------------------------------------
__global__ void convert_w(const float* __restrict__ qkv_w,
                          const float* __restrict__ proj_w,
                          __hip_bfloat16* __restrict__ Wq,
                          __hip_bfloat16* __restrict__ Wp) {
    int i = blockIdx.x * 256 + threadIdx.x;
    if (i < QKVC * Cdim) {
        Wq[i] = __float2bfloat16(qkv_w[i]);
    } else {
        int j = i - QKVC * Cdim;
        Wp[j] = __float2bfloat16(proj_w[j]);
    }
}

// ---------------------------------------------------------------------------
// posconv: depthwise 3x3 (zero pad) + bias + residual, f32 NCHW in ->
// bf16 NHWC out [NTOT][192]. Block = 64-pixel half-row x 192 channels.
// Phase 1: thread = (c, 4-pixel quad); per row one aligned float4 + 2
// boundary scalars; weights/bias cached in LDS (broadcast reads).
// Phase 2: LDS [c][pixel] -> packed 16B NHWC stores.
// ---------------------------------------------------------------------------
__global__ __launch_bounds__(256, 4)
void posconv_nhwc(const float* __restrict__ x,
                  const float* __restrict__ pos_w,
                  const float* __restrict__ pos_b,
                  __hip_bfloat16* __restrict__ Xb) {
    __shared__ __hip_bfloat16 tile[Cdim][68];   // [c][pixel], pad 64->68
    __shared__ float wts[Cdim * 9];
    __shared__ float bs[Cdim];
    int t = threadIdx.x;
    for (int i = t; i < Cdim * 9; i += 256) wts[i] = pos_w[i];
    if (t < Cdim) bs[t] = pos_b[t];
    __syncthreads();

    int p0 = blockIdx.x * 64;
    int b = p0 >> 14;
    int pimg = p0 & (HW - 1);
    int h = pimg >> 7, wbase = pimg & 127;      // 0 or 64
    const float* xim = x + (size_t)b * Cdim * HW;

#pragma unroll
    for (int it = 0; it < 12; ++it) {
        int quad = t & 15;
        int c = it * 16 + (t >> 4);
        int w0 = wbase + quad * 4;
        const float* xc = xim + (size_t)c * HW;
        const float* wt = wts + c * 9;
        float o0, o1, o2, o3;
        {   // center row: residual + bias + kh=1 taps
            const float* xr = xc + h * Wdim;
            float4 f = *(const float4*)(xr + w0);
            float L = (w0 > 0) ? xr[w0 - 1] : 0.f;
            float R = (w0 + 4 < Wdim) ? xr[w0 + 4] : 0.f;
            float b0 = bs[c];
            float w_0 = wt[3], w_1 = wt[4], w_2 = wt[5];
            o0 = f.x + b0 + w_0 * L   + w_1 * f.x + w_2 * f.y;
            o1 = f.y + b0 + w_0 * f.x + w_1 * f.y + w_2 * f.z;
            o2 = f.z + b0 + w_0 * f.y + w_1 * f.z + w_2 * f.w;
            o3 = f.w + b0 + w_0 * f.z + w_1 * f.w + w_2 * R;
        }
        if (h > 0) {   // row h-1, kh=0
            const float* xr = xc + (h - 1) * Wdim;
            float4 f = *(const float4*)(xr + w0);
            float L = (w0 > 0) ? xr[w0 - 1] : 0.f;
            float R = (w0 + 4 < Wdim) ? xr[w0 + 4] : 0.f;
            float w_0 = wt[0], w_1 = wt[1], w_2 = wt[2];
            o0 += w_0 * L   + w_1 * f.x + w_2 * f.y;
            o1 += w_0 * f.x + w_1 * f.y + w_2 * f.z;
            o2 += w_0 * f.y + w_1 * f.z + w_2 * f.w;
            o3 += w_0 * f.z + w_1 * f.w + w_2 * R;
        }
        if (h < Hdim - 1) {   // row h+1, kh=2
            const float* xr = xc + (h + 1) * Wdim;
            float4 f = *(const float4*)(xr + w0);
            float L = (w0 > 0) ? xr[w0 - 1] : 0.f;
            float R = (w0 + 4 < Wdim) ? xr[w0 + 4] : 0.f;
            float w_0 = wt[6], w_1 = wt[7], w_2 = wt[8];
            o0 += w_0 * L   + w_1 * f.x + w_2 * f.y;
            o1 += w_0 * f.x + w_1 * f.y + w_2 * f.z;
            o2 += w_0 * f.y + w_1 * f.z + w_2 * f.w;
            o3 += w_0 * f.z + w_1 * f.w + w_2 * R;
        }
        short4v pk;
        __hip_bfloat16 bv;
        bv = __float2bfloat16(o0); pk[0] = *(short*)&bv;
        bv = __float2bfloat16(o1); pk[1] = *(short*)&bv;
        bv = __float2bfloat16(o2); pk[2] = *(short*)&bv;
        bv = __float2bfloat16(o3); pk[3] = *(short*)&bv;
        *(short4v*)(void*)&tile[c][quad * 4] = pk;   // one ds_write_b64
    }
    __syncthreads();

    // phase 2: 1536 stores of 16B; lane = pixel (conflict-free LDS reads)
#pragma unroll
    for (int it = 0; it < 6; ++it) {
        int pl = t & 63;
        int cgq = it * 4 + (t >> 6);   // 0..23: channel octet
        union { unsigned short u[8]; short8 v; } o;
#pragma unroll
        for (int j = 0; j < 8; ++j)
            o.u[j] = *(const unsigned short*)&tile[cgq * 8 + j][pl];
        *(short8*)(void*)(Xb + (size_t)(p0 + pl) * Cdim + cgq * 8) = o.v;
    }
}

// ---------------------------------------------------------------------------
// MFMA bf16 GEMM: D[m,n] = sum_k W[m,k] * Xt[n,k]    (K = 192)
// Block 64x256 (4 waves of 64x64, 4x4 frags of 16x16x32). BK=32, 6 K-iters.
// MODE 0: store bf16 plane layout [(three*3+i)*2+nh][NTOT][32].
// MODE 1: store f32 NCHW out[b][m][p], col n = b*HW + p.
// ---------------------------------------------------------------------------
template <int MODE>
__global__ __launch_bounds__(256, 2)
void gemm_mfma(const __hip_bfloat16* __restrict__ Wb,
               const __hip_bfloat16* __restrict__ Xt,
               void* __restrict__ Cout) {
    __shared__ __hip_bfloat16 As[64 * 32];
    __shared__ __hip_bfloat16 Bs[256 * 32];
    const int t = threadIdx.x;
    const int w = t >> 6, l = t & 63;
    const int lq = l >> 4, lr = l & 15;
    const int m0 = blockIdx.y * 64;
    const int n0 = blockIdx.x * 256;

    f32x4 acc[4][4] = {};

    for (int kt = 0; kt < 6; ++kt) {
        const int k0 = kt * 32;
        {
            int m = t >> 2, kc = t & 3;
            async_ld16(As + t * 8, Wb + (size_t)(m0 + m) * Cdim + k0 + kc * 8);
        }
#pragma unroll
        for (int it = 0; it < 4; ++it) {
            int idx = it * 256 + t;
            int n = idx >> 2, kc = idx & 3;
            async_ld16(Bs + idx * 8, Xt + (size_t)(n0 + n) * Cdim + k0 + kc * 8);
        }
        __syncthreads();

        short8 af[4], bf[4];
#pragma unroll
        for (int i = 0; i < 4; ++i)
            af[i] = *(const short8*)(void*)(As + (i * 16 + lr) * 32 + lq * 8);
#pragma unroll
        for (int j = 0; j < 4; ++j)
            bf[j] = *(const short8*)(void*)(Bs + (w * 64 + j * 16 + lr) * 32 + lq * 8);
#pragma unroll
        for (int i = 0; i < 4; ++i)
#pragma unroll
            for (int j = 0; j < 4; ++j)
                acc[i][j] = __builtin_amdgcn_mfma_f32_16x16x32_bf16(
                    af[i], bf[j], acc[i][j], 0, 0, 0);
        __syncthreads();
    }

    // epilogue: D col = lane&15, row = (lane>>4)*4 + r  (m89/m91-verified)
#pragma unroll
    for (int i = 0; i < 4; ++i) {
        int mb = m0 + i * 16 + lq * 4;            // 4 consecutive m (r=0..3)
#pragma unroll
        for (int j = 0; j < 4; ++j) {
            int n = n0 + w * 64 + j * 16 + lr;
            if (MODE == 0) {
                int three = mb / 192, rem = mb % 192;
                int pi = rem >> 6, pn = (rem >> 5) & 1, d4 = rem & 31;
                size_t plane = (size_t)((three * 3 + pi) * 2 + pn);
                __hip_bfloat16* dst = (__hip_bfloat16*)Cout +
                    plane * ((size_t)NTOT * 32) + (size_t)n * 32 + d4;
                short4v pk;
#pragma unroll
                for (int r = 0; r < 4; ++r) {
                    __hip_bfloat16 bv = __float2bfloat16(acc[i][j][r]);
                    pk[r] = *(short*)&bv;
                }
                *(short4v*)(void*)dst = pk;
            } else {
                int b = n >> 14, p = n & (HW - 1);
#pragma unroll
                for (int r = 0; r < 4; ++r)
                    ((float*)Cout)[((size_t)(b * Cdim + mb + r)) * HW + p] =
                        acc[i][j][r];
            }
        }
    }
}

// ---------------------------------------------------------------------------
// Attention: one thread per (b, dilation i, head nh, pixel p).
// QKV bf16 planes [(three*3+i)*2+nh][NTOT][32]; per-thread Q/K/V rows are
// contiguous 64 B -> 4x dwordx4 loads. Output AO bf16 NHWC [NTOT][192].
// ---------------------------------------------------------------------------
__global__ __launch_bounds__(256, 2)
void attn_kernel(const __hip_bfloat16* __restrict__ QKV,
                 __hip_bfloat16* __restrict__ AO) {
    int t = threadIdx.x;
    int p = blockIdx.x * 256 + t;
    int comb = blockIdx.y;          // i*2 + nh
    int b = blockIdx.z;
    int i = comb >> 1, nh = comb & 1;
    int dil = i + 1;
    int h = p >> 7, w = p & 127;
    int col = (b << 14) + p;

    const size_t PS = (size_t)NTOT * 32;
    const __hip_bfloat16* Qp = QKV + (size_t)comb * PS;
    const __hip_bfloat16* Kp = Qp + 6 * PS;
    const __hip_bfloat16* Vp = Qp + 12 * PS;

    float q[32];
    {
        const uint4* qv = (const uint4*)(Qp + (size_t)col * 32);
#pragma unroll
        for (int u = 0; u < 4; ++u) {
            uint4 x = qv[u];
            q[u * 8 + 0] = lo16(x.x); q[u * 8 + 1] = hi16(x.x);
            q[u * 8 + 2] = lo16(x.y); q[u * 8 + 3] = hi16(x.y);
            q[u * 8 + 4] = lo16(x.z); q[u * 8 + 5] = hi16(x.z);
            q[u * 8 + 6] = lo16(x.w); q[u * 8 + 7] = hi16(x.w);
        }
    }

    // reflect-padded dilated 3x3 neighborhood (within the b-th image)
    int cj[9];
#pragma unroll
    for (int kh = 0; kh < 3; ++kh) {
        int hh = h + (kh - 1) * dil;
        hh = hh < 0 ? -hh : (hh >= Hdim ? 2 * Hdim - 2 - hh : hh);
#pragma unroll
        for (int kw = 0; kw < 3; ++kw) {
            int ww = w + (kw - 1) * dil;
            ww = ww < 0 ? -ww : (ww >= Wdim ? 2 * Wdim - 2 - ww : ww);
            cj[kh * 3 + kw] = (b << 14) + hh * Wdim + ww;
        }
    }

    float sc[9];
#pragma unroll
    for (int j = 0; j < 9; ++j) {
        const uint4* kv = (const uint4*)(Kp + (size_t)cj[j] * 32);
        float s = 0.f;
#pragma unroll
        for (int u = 0; u < 4; ++u) {
            uint4 x = kv[u];
            s += q[u * 8 + 0] * lo16(x.x) + q[u * 8 + 1] * hi16(x.x);
            s += q[u * 8 + 2] * lo16(x.y) + q[u * 8 + 3] * hi16(x.y);
            s += q[u * 8 + 4] * lo16(x.z) + q[u * 8 + 5] * hi16(x.z);
            s += q[u * 8 + 6] * lo16(x.w) + q[u * 8 + 7] * hi16(x.w);
        }
        sc[j] = s * 0.17677669529663687f;   // 32^-0.5
    }
    float m = sc[0];
#pragma unroll
    for (int j = 1; j < 9; ++j) m = fmaxf(m, sc[j]);
    float sum = 0.f;
#pragma unroll
    for (int j = 0; j < 9; ++j) { sc[j] = __expf(sc[j] - m); sum += sc[j]; }
    float inv = 1.f / sum;

    float acc[32] = {};
#pragma unroll
    for (int j = 0; j < 9; ++j) {
        const uint4* vv = (const uint4*)(Vp + (size_t)cj[j] * 32);
        float a = sc[j];
#pragma unroll
        for (int u = 0; u < 4; ++u) {
            uint4 x = vv[u];
            acc[u * 8 + 0] += a * lo16(x.x); acc[u * 8 + 1] += a * hi16(x.x);
            acc[u * 8 + 2] += a * lo16(x.y); acc[u * 8 + 3] += a * hi16(x.y);
            acc[u * 8 + 4] += a * lo16(x.z); acc[u * 8 + 5] += a * hi16(x.z);
            acc[u * 8 + 6] += a * lo16(x.w); acc[u * 8 + 7] += a * hi16(x.w);
        }
    }

    // NHWC store: 32 contiguous bf16 = 64 B, 16B-aligned
    union { unsigned short h[32]; short8 v[4]; } o;
#pragma unroll
    for (int d = 0; d < 32; ++d) {
        __hip_bfloat16 bv = __float2bfloat16(acc[d] * inv);
        o.h[d] = *(unsigned short*)&bv;
    }
    short8* dst = (short8*)(void*)(AO + (size_t)col * Cdim + i * 64 + nh * 32);
#pragma unroll
    for (int u = 0; u < 4; ++u) dst[u] = o.v[u];
}

// ---------------------------------------------------------------------------
extern "C" void kernel_launch(void* const* d_in, const int* in_sizes, int n_in,
                              void* d_out, int out_size, void* d_ws, size_t ws_size,
                              hipStream_t stream) {
    const float* x      = (const float*)d_in[0];
    const float* pos_w  = (const float*)d_in[1];
    const float* pos_b  = (const float*)d_in[2];
    const float* qkv_w  = (const float*)d_in[3];
    const float* proj_w = (const float*)d_in[4];
    float* out = (float*)d_out;

    // ws layout (bytes): Xb 24 MiB | QKV planes 72 MiB | AO 24 MiB | Wq | Wp
    char* ws = (char*)d_ws;
    __hip_bfloat16* Xb  = (__hip_bfloat16*)ws;                            // [NTOT][192]
    __hip_bfloat16* QKV = (__hip_bfloat16*)(ws + (size_t)25165824);       // [18][NTOT][32]
    __hip_bfloat16* AO  = (__hip_bfloat16*)(ws + (size_t)100663296);      // [NTOT][192]
    __hip_bfloat16* Wq  = (__hip_bfloat16*)(ws + (size_t)125829120);      // [576][192]
    __hip_bfloat16* Wp  = (__hip_bfloat16*)(ws + (size_t)126050304);      // [192][192]

    convert_w<<<(QKVC * Cdim + Cdim * Cdim) / 256, 256, 0, stream>>>(
        qkv_w, proj_w, Wq, Wp);

    posconv_nhwc<<<NTOT / 64, 256, 0, stream>>>(x, pos_w, pos_b, Xb);

    dim3 gq(NTOT / 256, QKVC / 64);
    gemm_mfma<0><<<gq, 256, 0, stream>>>(Wq, Xb, QKV);

    dim3 ga(HW / 256, 6, Bdim);
    attn_kernel<<<ga, 256, 0, stream>>>(QKV, AO);

    dim3 gp(NTOT / 256, Cdim / 64);
    gemm_mfma<1><<<gp, 256, 0, stream>>>(Wp, AO, out);
}

// Round 5
// 255.445 us; speedup vs baseline: 2.5737x; 1.0212x over previous
//
#include <hip/hip_runtime.h>
#include <hip/hip_bf16.h>
#include <math.h>

// Problem constants (B=4, C=192, H=W=128, KS=3, dilations {1,2,3}, 6 heads)
#define Hdim 128
#define Wdim 128
#define HW   16384
#define Cdim 192
#define Bdim 4
#define QKVC 576            // 3*C
#define NTOT (Bdim * HW)    // 65536 total pixels

typedef __attribute__((ext_vector_type(8))) short short8;   // 8 bf16 (4 VGPRs)
typedef __attribute__((ext_vector_type(4))) short short4v;  // 4 bf16 (8 B)
typedef __attribute__((ext_vector_type(4))) float f32x4;

__device__ __forceinline__ void async_ld16(void* lds, const void* g) {
    __builtin_amdgcn_global_load_lds(
        (const __attribute__((address_space(1))) void*)g,
        (__attribute__((address_space(3))) void*)lds, 16, 0, 0);
}
__device__ __forceinline__ float lo16(unsigned u) { return __uint_as_float(u << 16); }
__device__ __forceinline__ float hi16(unsigned u) { return __uint_as_float(u & 0xffff0000u); }

// ---------------------------------------------------------------------------
// Convert both weight matrices to bf16 (147456 elements total).
// ---------------------------------------------------------------------------
__global__ void convert_w(const float* __restrict__ qkv_w,
                          const float* __restrict__ proj_w,
                          __hip_bfloat16* __restrict__ Wq,
                          __hip_bfloat16* __restrict__ Wp) {
    int i = blockIdx.x * 256 + threadIdx.x;
    if (i < QKVC * Cdim) {
        Wq[i] = __float2bfloat16(qkv_w[i]);
    } else {
        int j = i - QKVC * Cdim;
        Wp[j] = __float2bfloat16(proj_w[j]);
    }
}

// ---------------------------------------------------------------------------
// posconv: depthwise 3x3 (zero pad) + bias + residual, f32 NCHW in ->
// bf16 NHWC out [NTOT][192]. Block = 64-pixel half-row x 192 channels.
// ---------------------------------------------------------------------------
__global__ __launch_bounds__(256, 4)
void posconv_nhwc(const float* __restrict__ x,
                  const float* __restrict__ pos_w,
                  const float* __restrict__ pos_b,
                  __hip_bfloat16* __restrict__ Xb) {
    __shared__ __hip_bfloat16 tile[Cdim][68];   // [c][pixel], pad 64->68
    __shared__ float wts[Cdim * 9];
    __shared__ float bs[Cdim];
    int t = threadIdx.x;
    for (int i = t; i < Cdim * 9; i += 256) wts[i] = pos_w[i];
    if (t < Cdim) bs[t] = pos_b[t];
    __syncthreads();

    int p0 = blockIdx.x * 64;
    int b = p0 >> 14;
    int pimg = p0 & (HW - 1);
    int h = pimg >> 7, wbase = pimg & 127;      // 0 or 64
    const float* xim = x + (size_t)b * Cdim * HW;

#pragma unroll
    for (int it = 0; it < 12; ++it) {
        int quad = t & 15;
        int c = it * 16 + (t >> 4);
        int w0 = wbase + quad * 4;
        const float* xc = xim + (size_t)c * HW;
        const float* wt = wts + c * 9;
        float o0, o1, o2, o3;
        {   // center row: residual + bias + kh=1 taps
            const float* xr = xc + h * Wdim;
            float4 f = *(const float4*)(xr + w0);
            float L = (w0 > 0) ? xr[w0 - 1] : 0.f;
            float R = (w0 + 4 < Wdim) ? xr[w0 + 4] : 0.f;
            float b0 = bs[c];
            float w_0 = wt[3], w_1 = wt[4], w_2 = wt[5];
            o0 = f.x + b0 + w_0 * L   + w_1 * f.x + w_2 * f.y;
            o1 = f.y + b0 + w_0 * f.x + w_1 * f.y + w_2 * f.z;
            o2 = f.z + b0 + w_0 * f.y + w_1 * f.z + w_2 * f.w;
            o3 = f.w + b0 + w_0 * f.z + w_1 * f.w + w_2 * R;
        }
        if (h > 0) {   // row h-1, kh=0
            const float* xr = xc + (h - 1) * Wdim;
            float4 f = *(const float4*)(xr + w0);
            float L = (w0 > 0) ? xr[w0 - 1] : 0.f;
            float R = (w0 + 4 < Wdim) ? xr[w0 + 4] : 0.f;
            float w_0 = wt[0], w_1 = wt[1], w_2 = wt[2];
            o0 += w_0 * L   + w_1 * f.x + w_2 * f.y;
            o1 += w_0 * f.x + w_1 * f.y + w_2 * f.z;
            o2 += w_0 * f.y + w_1 * f.z + w_2 * f.w;
            o3 += w_0 * f.z + w_1 * f.w + w_2 * R;
        }
        if (h < Hdim - 1) {   // row h+1, kh=2
            const float* xr = xc + (h + 1) * Wdim;
            float4 f = *(const float4*)(xr + w0);
            float L = (w0 > 0) ? xr[w0 - 1] : 0.f;
            float R = (w0 + 4 < Wdim) ? xr[w0 + 4] : 0.f;
            float w_0 = wt[6], w_1 = wt[7], w_2 = wt[8];
            o0 += w_0 * L   + w_1 * f.x + w_2 * f.y;
            o1 += w_0 * f.x + w_1 * f.y + w_2 * f.z;
            o2 += w_0 * f.y + w_1 * f.z + w_2 * f.w;
            o3 += w_0 * f.z + w_1 * f.w + w_2 * R;
        }
        short4v pk;
        __hip_bfloat16 bv;
        bv = __float2bfloat16(o0); pk[0] = *(short*)&bv;
        bv = __float2bfloat16(o1); pk[1] = *(short*)&bv;
        bv = __float2bfloat16(o2); pk[2] = *(short*)&bv;
        bv = __float2bfloat16(o3); pk[3] = *(short*)&bv;
        *(short4v*)(void*)&tile[c][quad * 4] = pk;   // one ds_write_b64
    }
    __syncthreads();

    // phase 2: 1536 stores of 16B; lane = pixel (conflict-free LDS reads)
#pragma unroll
    for (int it = 0; it < 6; ++it) {
        int pl = t & 63;
        int cgq = it * 4 + (t >> 6);   // 0..23: channel octet
        union { unsigned short u[8]; short8 v; } o;
#pragma unroll
        for (int j = 0; j < 8; ++j)
            o.u[j] = *(const unsigned short*)&tile[cgq * 8 + j][pl];
        *(short8*)(void*)(Xb + (size_t)(p0 + pl) * Cdim + cgq * 8) = o.v;
    }
}

// ---------------------------------------------------------------------------
// MFMA bf16 GEMM: D[m,n] = sum_k W[m,k] * Xt[n,k]    (K = 192)
// Block 64x256 (4 waves of 64x64, 4x4 frags of 16x16x32). BK=32, 6 K-iters.
// MODE 0: B = NHWC [NTOT][192]; store bf16 planes [(three*3+i)*2+nh][NTOT][32].
// MODE 1: B = planes [6][NTOT][32] (K-chunk kt == plane kt);
//         store f32 NCHW out[b][m][p], col n = b*HW + p.
// ---------------------------------------------------------------------------
template <int MODE>
__global__ __launch_bounds__(256, 2)
void gemm_mfma(const __hip_bfloat16* __restrict__ Wb,
               const __hip_bfloat16* __restrict__ Xt,
               void* __restrict__ Cout) {
    __shared__ __hip_bfloat16 As[64 * 32];
    __shared__ __hip_bfloat16 Bs[256 * 32];
    const int t = threadIdx.x;
    const int w = t >> 6, l = t & 63;
    const int lq = l >> 4, lr = l & 15;
    const int m0 = blockIdx.y * 64;
    const int n0 = blockIdx.x * 256;

    f32x4 acc[4][4] = {};

    for (int kt = 0; kt < 6; ++kt) {
        const int k0 = kt * 32;
        {
            int m = t >> 2, kc = t & 3;
            async_ld16(As + t * 8, Wb + (size_t)(m0 + m) * Cdim + k0 + kc * 8);
        }
#pragma unroll
        for (int it = 0; it < 4; ++it) {
            int idx = it * 256 + t;
            int n = idx >> 2, kc = idx & 3;
            const __hip_bfloat16* src;
            if (MODE == 0)
                src = Xt + (size_t)(n0 + n) * Cdim + k0 + kc * 8;
            else
                src = Xt + (size_t)kt * ((size_t)NTOT * 32) +
                      (size_t)(n0 + n) * 32 + kc * 8;
            async_ld16(Bs + idx * 8, src);
        }
        __syncthreads();

        short8 af[4], bf[4];
#pragma unroll
        for (int i = 0; i < 4; ++i)
            af[i] = *(const short8*)(void*)(As + (i * 16 + lr) * 32 + lq * 8);
#pragma unroll
        for (int j = 0; j < 4; ++j)
            bf[j] = *(const short8*)(void*)(Bs + (w * 64 + j * 16 + lr) * 32 + lq * 8);
#pragma unroll
        for (int i = 0; i < 4; ++i)
#pragma unroll
            for (int j = 0; j < 4; ++j)
                acc[i][j] = __builtin_amdgcn_mfma_f32_16x16x32_bf16(
                    af[i], bf[j], acc[i][j], 0, 0, 0);
        __syncthreads();
    }

    // epilogue: D col = lane&15, row = (lane>>4)*4 + r  (m89/m91-verified)
#pragma unroll
    for (int i = 0; i < 4; ++i) {
        int mb = m0 + i * 16 + lq * 4;            // 4 consecutive m (r=0..3)
#pragma unroll
        for (int j = 0; j < 4; ++j) {
            int n = n0 + w * 64 + j * 16 + lr;
            if (MODE == 0) {
                int three = mb / 192, rem = mb % 192;
                int pi = rem >> 6, pn = (rem >> 5) & 1, d4 = rem & 31;
                size_t plane = (size_t)((three * 3 + pi) * 2 + pn);
                __hip_bfloat16* dst = (__hip_bfloat16*)Cout +
                    plane * ((size_t)NTOT * 32) + (size_t)n * 32 + d4;
                short4v pk;
#pragma unroll
                for (int r = 0; r < 4; ++r) {
                    __hip_bfloat16 bv = __float2bfloat16(acc[i][j][r]);
                    pk[r] = *(short*)&bv;
                }
                *(short4v*)(void*)dst = pk;
            } else {
                int b = n >> 14, p = n & (HW - 1);
#pragma unroll
                for (int r = 0; r < 4; ++r)
                    ((float*)Cout)[((size_t)(b * Cdim + mb + r)) * HW + p] =
                        acc[i][j][r];
            }
        }
    }
}

// ---------------------------------------------------------------------------
// Attention: one thread per (b, dilation i, head nh, pixel p).
// QKV bf16 planes [18][NTOT][32]; AO bf16 planes [6][NTOT][32].
// Flat 1-D grid with XCD swizzle: 8 consecutive pixel-blocks of one
// (b,comb) land on one XCD (n%8 placement heuristic) for K/V L2 reuse.
// ---------------------------------------------------------------------------
__global__ __launch_bounds__(256, 2)
void attn_kernel(const __hip_bfloat16* __restrict__ QKV,
                 __hip_bfloat16* __restrict__ AO) {
    int t = threadIdx.x;
    int id = blockIdx.x;                 // 0..1535
    int xj = id & 7;                     // target XCD
    int rest = id >> 3;
    int k8 = rest & 7;
    int cb = rest >> 3;                  // 0..23 = b*6 + comb
    int gx = xj * 8 + k8;                // pixel-block 0..63
    int b = cb / 6, comb = cb % 6;
    int i = comb >> 1, nh = comb & 1;
    int dil = i + 1;

    int p = gx * 256 + t;
    int h = p >> 7, w = p & 127;
    int col = (b << 14) + p;

    const size_t PS = (size_t)NTOT * 32;
    const __hip_bfloat16* Qp = QKV + (size_t)comb * PS;
    const __hip_bfloat16* Kp = Qp + 6 * PS;
    const __hip_bfloat16* Vp = Qp + 12 * PS;

    float q[32];
    {
        const uint4* qv = (const uint4*)(Qp + (size_t)col * 32);
#pragma unroll
        for (int u = 0; u < 4; ++u) {
            uint4 x = qv[u];
            q[u * 8 + 0] = lo16(x.x); q[u * 8 + 1] = hi16(x.x);
            q[u * 8 + 2] = lo16(x.y); q[u * 8 + 3] = hi16(x.y);
            q[u * 8 + 4] = lo16(x.z); q[u * 8 + 5] = hi16(x.z);
            q[u * 8 + 6] = lo16(x.w); q[u * 8 + 7] = hi16(x.w);
        }
    }

    // reflect-padded dilated 3x3 neighborhood (within the b-th image)
    int cj[9];
#pragma unroll
    for (int kh = 0; kh < 3; ++kh) {
        int hh = h + (kh - 1) * dil;
        hh = hh < 0 ? -hh : (hh >= Hdim ? 2 * Hdim - 2 - hh : hh);
#pragma unroll
        for (int kw = 0; kw < 3; ++kw) {
            int ww = w + (kw - 1) * dil;
            ww = ww < 0 ? -ww : (ww >= Wdim ? 2 * Wdim - 2 - ww : ww);
            cj[kh * 3 + kw] = (b << 14) + hh * Wdim + ww;
        }
    }

    float sc[9];
#pragma unroll
    for (int j = 0; j < 9; ++j) {
        const uint4* kv = (const uint4*)(Kp + (size_t)cj[j] * 32);
        float s = 0.f;
#pragma unroll
        for (int u = 0; u < 4; ++u) {
            uint4 x = kv[u];
            s += q[u * 8 + 0] * lo16(x.x) + q[u * 8 + 1] * hi16(x.x);
            s += q[u * 8 + 2] * lo16(x.y) + q[u * 8 + 3] * hi16(x.y);
            s += q[u * 8 + 4] * lo16(x.z) + q[u * 8 + 5] * hi16(x.z);
            s += q[u * 8 + 6] * lo16(x.w) + q[u * 8 + 7] * hi16(x.w);
        }
        sc[j] = s * 0.17677669529663687f;   // 32^-0.5
    }
    float m = sc[0];
#pragma unroll
    for (int j = 1; j < 9; ++j) m = fmaxf(m, sc[j]);
    float sum = 0.f;
#pragma unroll
    for (int j = 0; j < 9; ++j) { sc[j] = __expf(sc[j] - m); sum += sc[j]; }
    float inv = 1.f / sum;

    float acc[32] = {};
#pragma unroll
    for (int j = 0; j < 9; ++j) {
        const uint4* vv = (const uint4*)(Vp + (size_t)cj[j] * 32);
        float a = sc[j];
#pragma unroll
        for (int u = 0; u < 4; ++u) {
            uint4 x = vv[u];
            acc[u * 8 + 0] += a * lo16(x.x); acc[u * 8 + 1] += a * hi16(x.x);
            acc[u * 8 + 2] += a * lo16(x.y); acc[u * 8 + 3] += a * hi16(x.y);
            acc[u * 8 + 4] += a * lo16(x.z); acc[u * 8 + 5] += a * hi16(x.z);
            acc[u * 8 + 6] += a * lo16(x.w); acc[u * 8 + 7] += a * hi16(x.w);
        }
    }

    // plane store: 64 contiguous B/thread, wave = 4 KB dense (full lines)
    union { unsigned short h[32]; short8 v[4]; } o;
#pragma unroll
    for (int d = 0; d < 32; ++d) {
        __hip_bfloat16 bv = __float2bfloat16(acc[d] * inv);
        o.h[d] = *(unsigned short*)&bv;
    }
    short8* dst = (short8*)(void*)(AO + (size_t)comb * PS + (size_t)col * 32);
#pragma unroll
    for (int u = 0; u < 4; ++u) dst[u] = o.v[u];
}

// ---------------------------------------------------------------------------
extern "C" void kernel_launch(void* const* d_in, const int* in_sizes, int n_in,
                              void* d_out, int out_size, void* d_ws, size_t ws_size,
                              hipStream_t stream) {
    const float* x      = (const float*)d_in[0];
    const float* pos_w  = (const float*)d_in[1];
    const float* pos_b  = (const float*)d_in[2];
    const float* qkv_w  = (const float*)d_in[3];
    const float* proj_w = (const float*)d_in[4];
    float* out = (float*)d_out;

    // ws layout (bytes): Xb 24 MiB | QKV planes 72 MiB | AO planes 24 MiB | Wq | Wp
    char* ws = (char*)d_ws;
    __hip_bfloat16* Xb  = (__hip_bfloat16*)ws;                            // [NTOT][192]
    __hip_bfloat16* QKV = (__hip_bfloat16*)(ws + (size_t)25165824);       // [18][NTOT][32]
    __hip_bfloat16* AO  = (__hip_bfloat16*)(ws + (size_t)100663296);      // [6][NTOT][32]
    __hip_bfloat16* Wq  = (__hip_bfloat16*)(ws + (size_t)125829120);      // [576][192]
    __hip_bfloat16* Wp  = (__hip_bfloat16*)(ws + (size_t)126050304);      // [192][192]

    convert_w<<<(QKVC * Cdim + Cdim * Cdim) / 256, 256, 0, stream>>>(
        qkv_w, proj_w, Wq, Wp);

    posconv_nhwc<<<NTOT / 64, 256, 0, stream>>>(x, pos_w, pos_b, Xb);

    dim3 gq(NTOT / 256, QKVC / 64);
    gemm_mfma<0><<<gq, 256, 0, stream>>>(Wq, Xb, QKV);

    attn_kernel<<<1536, 256, 0, stream>>>(QKV, AO);

    dim3 gp(NTOT / 256, Cdim / 64);
    gemm_mfma<1><<<gp, 256, 0, stream>>>(Wp, AO, out);
}

// Round 6
// 240.969 us; speedup vs baseline: 2.7283x; 1.0601x over previous
//
#include <hip/hip_runtime.h>
#include <hip/hip_bf16.h>
#include <math.h>

// Problem constants (B=4, C=192, H=W=128, KS=3, dilations {1,2,3}, 6 heads)
#define Hdim 128
#define Wdim 128
#define HW   16384
#define Cdim 192
#define Bdim 4
#define QKVC 576            // 3*C
#define NTOT (Bdim * HW)    // 65536 total pixels

typedef __attribute__((ext_vector_type(8))) short short8;   // 8 bf16 (4 VGPRs)
typedef __attribute__((ext_vector_type(4))) short short4v;  // 4 bf16 (8 B)
typedef __attribute__((ext_vector_type(4))) float f32x4;

__device__ __forceinline__ void async_ld16(void* lds, const void* g) {
    __builtin_amdgcn_global_load_lds(
        (const __attribute__((address_space(1))) void*)g,
        (__attribute__((address_space(3))) void*)lds, 16, 0, 0);
}
__device__ __forceinline__ float lo16(unsigned u) { return __uint_as_float(u << 16); }
__device__ __forceinline__ float hi16(unsigned u) { return __uint_as_float(u & 0xffff0000u); }

// ---------------------------------------------------------------------------
// Convert both weight matrices to bf16 (147456 elements total).
// ---------------------------------------------------------------------------
__global__ void convert_w(const float* __restrict__ qkv_w,
                          const float* __restrict__ proj_w,
                          __hip_bfloat16* __restrict__ Wq,
                          __hip_bfloat16* __restrict__ Wp) {
    int i = blockIdx.x * 256 + threadIdx.x;
    if (i < QKVC * Cdim) {
        Wq[i] = __float2bfloat16(qkv_w[i]);
    } else {
        int j = i - QKVC * Cdim;
        Wp[j] = __float2bfloat16(proj_w[j]);
    }
}

// ---------------------------------------------------------------------------
// posconv: depthwise 3x3 (zero pad) + bias + residual, f32 NCHW in ->
// bf16 NHWC out [NTOT][192]. Block = 64-pixel half-row x 192 channels.
// ---------------------------------------------------------------------------
__global__ __launch_bounds__(256, 4)
void posconv_nhwc(const float* __restrict__ x,
                  const float* __restrict__ pos_w,
                  const float* __restrict__ pos_b,
                  __hip_bfloat16* __restrict__ Xb) {
    __shared__ __hip_bfloat16 tile[Cdim][68];   // [c][pixel], pad 64->68
    __shared__ float wts[Cdim * 9];
    __shared__ float bs[Cdim];
    int t = threadIdx.x;
    for (int i = t; i < Cdim * 9; i += 256) wts[i] = pos_w[i];
    if (t < Cdim) bs[t] = pos_b[t];
    __syncthreads();

    int p0 = blockIdx.x * 64;
    int b = p0 >> 14;
    int pimg = p0 & (HW - 1);
    int h = pimg >> 7, wbase = pimg & 127;      // 0 or 64
    const float* xim = x + (size_t)b * Cdim * HW;

#pragma unroll
    for (int it = 0; it < 12; ++it) {
        int quad = t & 15;
        int c = it * 16 + (t >> 4);
        int w0 = wbase + quad * 4;
        const float* xc = xim + (size_t)c * HW;
        const float* wt = wts + c * 9;
        float o0, o1, o2, o3;
        {   // center row: residual + bias + kh=1 taps
            const float* xr = xc + h * Wdim;
            float4 f = *(const float4*)(xr + w0);
            float L = (w0 > 0) ? xr[w0 - 1] : 0.f;
            float R = (w0 + 4 < Wdim) ? xr[w0 + 4] : 0.f;
            float b0 = bs[c];
            float w_0 = wt[3], w_1 = wt[4], w_2 = wt[5];
            o0 = f.x + b0 + w_0 * L   + w_1 * f.x + w_2 * f.y;
            o1 = f.y + b0 + w_0 * f.x + w_1 * f.y + w_2 * f.z;
            o2 = f.z + b0 + w_0 * f.y + w_1 * f.z + w_2 * f.w;
            o3 = f.w + b0 + w_0 * f.z + w_1 * f.w + w_2 * R;
        }
        if (h > 0) {   // row h-1, kh=0
            const float* xr = xc + (h - 1) * Wdim;
            float4 f = *(const float4*)(xr + w0);
            float L = (w0 > 0) ? xr[w0 - 1] : 0.f;
            float R = (w0 + 4 < Wdim) ? xr[w0 + 4] : 0.f;
            float w_0 = wt[0], w_1 = wt[1], w_2 = wt[2];
            o0 += w_0 * L   + w_1 * f.x + w_2 * f.y;
            o1 += w_0 * f.x + w_1 * f.y + w_2 * f.z;
            o2 += w_0 * f.y + w_1 * f.z + w_2 * f.w;
            o3 += w_0 * f.z + w_1 * f.w + w_2 * R;
        }
        if (h < Hdim - 1) {   // row h+1, kh=2
            const float* xr = xc + (h + 1) * Wdim;
            float4 f = *(const float4*)(xr + w0);
            float L = (w0 > 0) ? xr[w0 - 1] : 0.f;
            float R = (w0 + 4 < Wdim) ? xr[w0 + 4] : 0.f;
            float w_0 = wt[6], w_1 = wt[7], w_2 = wt[8];
            o0 += w_0 * L   + w_1 * f.x + w_2 * f.y;
            o1 += w_0 * f.x + w_1 * f.y + w_2 * f.z;
            o2 += w_0 * f.y + w_1 * f.z + w_2 * f.w;
            o3 += w_0 * f.z + w_1 * f.w + w_2 * R;
        }
        short4v pk;
        __hip_bfloat16 bv;
        bv = __float2bfloat16(o0); pk[0] = *(short*)&bv;
        bv = __float2bfloat16(o1); pk[1] = *(short*)&bv;
        bv = __float2bfloat16(o2); pk[2] = *(short*)&bv;
        bv = __float2bfloat16(o3); pk[3] = *(short*)&bv;
        *(short4v*)(void*)&tile[c][quad * 4] = pk;   // one ds_write_b64
    }
    __syncthreads();

    // phase 2: 1536 stores of 16B; lane = pixel (conflict-free LDS reads)
#pragma unroll
    for (int it = 0; it < 6; ++it) {
        int pl = t & 63;
        int cgq = it * 4 + (t >> 6);   // 0..23: channel octet
        union { unsigned short u[8]; short8 v; } o;
#pragma unroll
        for (int j = 0; j < 8; ++j)
            o.u[j] = *(const unsigned short*)&tile[cgq * 8 + j][pl];
        *(short8*)(void*)(Xb + (size_t)(p0 + pl) * Cdim + cgq * 8) = o.v;
    }
}

// ---------------------------------------------------------------------------
// MFMA bf16 GEMM: D[m,n] = sum_k W[m,k] * Xt[n,k]    (K = 192)
// Block 64x256 (4 waves of 64x64, 4x4 frags of 16x16x32). BK=32, 6 K-iters.
// 1-D grid, XCD-aware decode: each XCD runs all MT m-tiles of one n-block
// consecutively -> B-tile fetched into its L2 once, reused MT times.
// MODE 0: B = NHWC [NTOT][192]; store bf16 planes [(three*3+i)*2+nh][NTOT][32].
// MODE 1: B = planes [6][NTOT][32] (K-chunk kt == plane kt);
//         store f32 NCHW out[b][m][p], col n = b*HW + p.
// ---------------------------------------------------------------------------
template <int MODE, int MT>
__global__ __launch_bounds__(256, 2)
void gemm_mfma(const __hip_bfloat16* __restrict__ Wb,
               const __hip_bfloat16* __restrict__ Xt,
               void* __restrict__ Cout) {
    __shared__ __hip_bfloat16 As[64 * 32];
    __shared__ __hip_bfloat16 Bs[256 * 32];
    const int t = threadIdx.x;
    const int w = t >> 6, l = t & 63;
    const int lq = l >> 4, lr = l & 15;
    const int id = blockIdx.x;
    const int xj = id & 7;                 // XCD (dispatch round-robin)
    const int rest = id >> 3;
    const int m0 = (rest % MT) * 64;
    const int n0 = ((rest / MT) * 8 + xj) * 256;

    f32x4 acc[4][4] = {};

    for (int kt = 0; kt < 6; ++kt) {
        const int k0 = kt * 32;
        {
            int m = t >> 2, kc = t & 3;
            async_ld16(As + t * 8, Wb + (size_t)(m0 + m) * Cdim + k0 + kc * 8);
        }
#pragma unroll
        for (int it = 0; it < 4; ++it) {
            int idx = it * 256 + t;
            int n = idx >> 2, kc = idx & 3;
            const __hip_bfloat16* src;
            if (MODE == 0)
                src = Xt + (size_t)(n0 + n) * Cdim + k0 + kc * 8;
            else
                src = Xt + (size_t)kt * ((size_t)NTOT * 32) +
                      (size_t)(n0 + n) * 32 + kc * 8;
            async_ld16(Bs + idx * 8, src);
        }
        __syncthreads();

        short8 af[4], bf[4];
#pragma unroll
        for (int i = 0; i < 4; ++i)
            af[i] = *(const short8*)(void*)(As + (i * 16 + lr) * 32 + lq * 8);
#pragma unroll
        for (int j = 0; j < 4; ++j)
            bf[j] = *(const short8*)(void*)(Bs + (w * 64 + j * 16 + lr) * 32 + lq * 8);
#pragma unroll
        for (int i = 0; i < 4; ++i)
#pragma unroll
            for (int j = 0; j < 4; ++j)
                acc[i][j] = __builtin_amdgcn_mfma_f32_16x16x32_bf16(
                    af[i], bf[j], acc[i][j], 0, 0, 0);
        __syncthreads();
    }

    // epilogue: D col = lane&15, row = (lane>>4)*4 + r  (m89/m91-verified)
#pragma unroll
    for (int i = 0; i < 4; ++i) {
        int mb = m0 + i * 16 + lq * 4;            // 4 consecutive m (r=0..3)
#pragma unroll
        for (int j = 0; j < 4; ++j) {
            int n = n0 + w * 64 + j * 16 + lr;
            if (MODE == 0) {
                int three = mb / 192, rem = mb % 192;
                int pi = rem >> 6, pn = (rem >> 5) & 1, d4 = rem & 31;
                size_t plane = (size_t)((three * 3 + pi) * 2 + pn);
                __hip_bfloat16* dst = (__hip_bfloat16*)Cout +
                    plane * ((size_t)NTOT * 32) + (size_t)n * 32 + d4;
                short4v pk;
#pragma unroll
                for (int r = 0; r < 4; ++r) {
                    __hip_bfloat16 bv = __float2bfloat16(acc[i][j][r]);
                    pk[r] = *(short*)&bv;
                }
                *(short4v*)(void*)dst = pk;
            } else {
                int b = n >> 14, p = n & (HW - 1);
#pragma unroll
                for (int r = 0; r < 4; ++r)
                    ((float*)Cout)[((size_t)(b * Cdim + mb + r)) * HW + p] =
                        acc[i][j][r];
            }
        }
    }
}

// ---------------------------------------------------------------------------
// Attention, d-split: lane pair = one pixel, each lane owns 16 of 32 dims.
// Block = 1 image row (128 px x 2 slices). QKV/AO bf16 planes [*][NTOT][32].
// Score = partial dot + shfl_xor(1) butterfly; softmax per-lane (redundant).
// XCD swizzle: each XCD gets 16 adjacent rows per (b,comb) -> K/V L2 reuse.
// ---------------------------------------------------------------------------
__global__ __launch_bounds__(256, 4)
void attn_kernel(const __hip_bfloat16* __restrict__ QKV,
                 __hip_bfloat16* __restrict__ AO) {
    int t = threadIdx.x;
    int pix = t >> 1, s = t & 1;
    int id = blockIdx.x;                 // 0..3071
    int xj = id & 7;                     // XCD
    int rest = id >> 3;                  // 0..383
    int cb = rest >> 4;                  // 0..23 = b*6 + comb
    int k16 = rest & 15;
    int h = xj * 16 + k16;               // image row 0..127
    int b = cb / 6, comb = cb % 6;
    int dil = (comb >> 1) + 1;

    int w = pix;
    int col = (b << 14) + h * Wdim + w;

    const size_t PS = (size_t)NTOT * 32;
    const __hip_bfloat16* Qp = QKV + (size_t)comb * PS;
    const __hip_bfloat16* Kp = Qp + 6 * PS;
    const __hip_bfloat16* Vp = Qp + 12 * PS;

    // q slice: 16 dims (global d = s*16 + 0..15), 2x 16B loads
    float q[16];
    {
        const uint4* qv = (const uint4*)(Qp + (size_t)col * 32) + s * 2;
#pragma unroll
        for (int u = 0; u < 2; ++u) {
            uint4 x = qv[u];
            q[u * 8 + 0] = lo16(x.x); q[u * 8 + 1] = hi16(x.x);
            q[u * 8 + 2] = lo16(x.y); q[u * 8 + 3] = hi16(x.y);
            q[u * 8 + 4] = lo16(x.z); q[u * 8 + 5] = hi16(x.z);
            q[u * 8 + 6] = lo16(x.w); q[u * 8 + 7] = hi16(x.w);
        }
    }

    // reflect-padded dilated 3x3 neighborhood (within the b-th image)
    int cj[9];
#pragma unroll
    for (int kh = 0; kh < 3; ++kh) {
        int hh = h + (kh - 1) * dil;
        hh = hh < 0 ? -hh : (hh >= Hdim ? 2 * Hdim - 2 - hh : hh);
#pragma unroll
        for (int kw = 0; kw < 3; ++kw) {
            int ww = w + (kw - 1) * dil;
            ww = ww < 0 ? -ww : (ww >= Wdim ? 2 * Wdim - 2 - ww : ww);
            cj[kh * 3 + kw] = (b << 14) + hh * Wdim + ww;
        }
    }

    float sc[9];
#pragma unroll
    for (int j = 0; j < 9; ++j) {
        const uint4* kv = (const uint4*)(Kp + (size_t)cj[j] * 32) + s * 2;
        float p0 = 0.f;
#pragma unroll
        for (int u = 0; u < 2; ++u) {
            uint4 x = kv[u];
            p0 += q[u * 8 + 0] * lo16(x.x) + q[u * 8 + 1] * hi16(x.x);
            p0 += q[u * 8 + 2] * lo16(x.y) + q[u * 8 + 3] * hi16(x.y);
            p0 += q[u * 8 + 4] * lo16(x.z) + q[u * 8 + 5] * hi16(x.z);
            p0 += q[u * 8 + 6] * lo16(x.w) + q[u * 8 + 7] * hi16(x.w);
        }
        sc[j] = p0;
    }
    // butterfly: both lanes of the pair get the full 32-d dot
#pragma unroll
    for (int j = 0; j < 9; ++j)
        sc[j] = (sc[j] + __shfl_xor(sc[j], 1, 64)) * 0.17677669529663687f;

    float m = sc[0];
#pragma unroll
    for (int j = 1; j < 9; ++j) m = fmaxf(m, sc[j]);
    float sum = 0.f;
#pragma unroll
    for (int j = 0; j < 9; ++j) { sc[j] = __expf(sc[j] - m); sum += sc[j]; }
    float inv = 1.f / sum;

    float acc[16] = {};
#pragma unroll
    for (int j = 0; j < 9; ++j) {
        const uint4* vv = (const uint4*)(Vp + (size_t)cj[j] * 32) + s * 2;
        float a = sc[j];
#pragma unroll
        for (int u = 0; u < 2; ++u) {
            uint4 x = vv[u];
            acc[u * 8 + 0] += a * lo16(x.x); acc[u * 8 + 1] += a * hi16(x.x);
            acc[u * 8 + 2] += a * lo16(x.y); acc[u * 8 + 3] += a * hi16(x.y);
            acc[u * 8 + 4] += a * lo16(x.z); acc[u * 8 + 5] += a * hi16(x.z);
            acc[u * 8 + 6] += a * lo16(x.w); acc[u * 8 + 7] += a * hi16(x.w);
        }
    }

    // plane store: 32 B/thread, wave = 4 KB dense (full lines)
    union { unsigned short h[16]; short8 v[2]; } o;
#pragma unroll
    for (int d = 0; d < 16; ++d) {
        __hip_bfloat16 bv = __float2bfloat16(acc[d] * inv);
        o.h[d] = *(unsigned short*)&bv;
    }
    short8* dst = (short8*)(void*)(AO + (size_t)comb * PS + (size_t)col * 32 + s * 16);
#pragma unroll
    for (int u = 0; u < 2; ++u) dst[u] = o.v[u];
}

// ---------------------------------------------------------------------------
extern "C" void kernel_launch(void* const* d_in, const int* in_sizes, int n_in,
                              void* d_out, int out_size, void* d_ws, size_t ws_size,
                              hipStream_t stream) {
    const float* x      = (const float*)d_in[0];
    const float* pos_w  = (const float*)d_in[1];
    const float* pos_b  = (const float*)d_in[2];
    const float* qkv_w  = (const float*)d_in[3];
    const float* proj_w = (const float*)d_in[4];
    float* out = (float*)d_out;

    // ws layout (bytes): Xb 24 MiB | QKV planes 72 MiB | AO planes 24 MiB | Wq | Wp
    char* ws = (char*)d_ws;
    __hip_bfloat16* Xb  = (__hip_bfloat16*)ws;                            // [NTOT][192]
    __hip_bfloat16* QKV = (__hip_bfloat16*)(ws + (size_t)25165824);       // [18][NTOT][32]
    __hip_bfloat16* AO  = (__hip_bfloat16*)(ws + (size_t)100663296);      // [6][NTOT][32]
    __hip_bfloat16* Wq  = (__hip_bfloat16*)(ws + (size_t)125829120);      // [576][192]
    __hip_bfloat16* Wp  = (__hip_bfloat16*)(ws + (size_t)126050304);      // [192][192]

    convert_w<<<(QKVC * Cdim + Cdim * Cdim) / 256, 256, 0, stream>>>(
        qkv_w, proj_w, Wq, Wp);

    posconv_nhwc<<<NTOT / 64, 256, 0, stream>>>(x, pos_w, pos_b, Xb);

    gemm_mfma<0, 9><<<2304, 256, 0, stream>>>(Wq, Xb, QKV);

    attn_kernel<<<3072, 256, 0, stream>>>(QKV, AO);

    gemm_mfma<1, 3><<<768, 256, 0, stream>>>(Wp, AO, out);
}